// Round 1
// baseline (190.219 us; speedup 1.0000x reference)
//
#include <hip/hip_runtime.h>
#include <hip/hip_fp16.h>
#include <cstdint>
#include <cstddef>

// FastGRNN cell, MI355X fp16-MFMA implementation.
// r = [x@W1^T | h@U1^T]  (f16, in d_ws)
// pre = r @ [W2|U2]^T  ; out = sigmoid(pre+bg)*h + (sz*(1-sigmoid(pre+bg))+sn)*tanh(pre+bu)

typedef _Float16 half8 __attribute__((ext_vector_type(8)));
typedef float f32x4 __attribute__((ext_vector_type(4)));

#define DIN 1024
#define DH 2048
#define RK 256
#define RB_LD 512  // rbuf leading dim (wRank cols 0..255, uRank cols 256..511)

__device__ __forceinline__ half8 cvt8(const float4 a, const float4 b) {
  half8 h;
  h[0] = (_Float16)a.x; h[1] = (_Float16)a.y; h[2] = (_Float16)a.z; h[3] = (_Float16)a.w;
  h[4] = (_Float16)b.x; h[5] = (_Float16)b.y; h[6] = (_Float16)b.z; h[7] = (_Float16)b.w;
  return h;
}

// ---------------- stage 1: twin low-rank projection GEMMs -------------------
// grid = 512 blocks of 256 threads. p = bid>>8 selects (x,W1,K=1024) vs (h,U1,K=2048).
// Tile: BM=128, BN=64, BK=64. 4 waves in 2x2; each wave owns 64x32 (acc[4][2]).
__global__ __launch_bounds__(256)
void fgrnn_stage1(const float* __restrict__ x, const float* __restrict__ h,
                  const float* __restrict__ W1, const float* __restrict__ U1,
                  _Float16* __restrict__ rbuf) {
  const int bid = blockIdx.x;
  const int p = bid >> 8;           // 0: x@W1^T  1: h@U1^T
  const int loc = bid & 255;
  const int mtile = loc >> 2;       // 0..63
  const int ntile = loc & 3;        // 0..3
  const int K = p ? DH : DIN;
  const float* A = p ? h : x;
  const float* Bw = p ? U1 : W1;
  const int row0 = mtile * 128;
  const int nrow0 = ntile * 64;
  const int colbase = p * 256 + ntile * 64;

  __shared__ _Float16 As[128 * 64];
  __shared__ _Float16 Bs[64 * 64];

  const int tid = threadIdx.x;
  const int lane = tid & 63;
  const int w = tid >> 6;
  const int wr = w >> 1;  // 0..1
  const int wc = w & 1;   // 0..1

  f32x4 acc[4][2];
#pragma unroll
  for (int i = 0; i < 4; ++i) {
#pragma unroll
    for (int j = 0; j < 2; ++j) acc[i][j] = (f32x4){0.f, 0.f, 0.f, 0.f};
  }

  for (int k0 = 0; k0 < K; k0 += 64) {
    // A tile: 128x64 f32 -> f16 LDS (row-major [128][64])
#pragma unroll
    for (int j = 0; j < 4; ++j) {
      const int flat = j * 2048 + tid * 8;
      const int r = flat >> 6, c = flat & 63;
      const float4* s = reinterpret_cast<const float4*>(A + (size_t)(row0 + r) * K + k0 + c);
      *reinterpret_cast<half8*>(&As[flat]) = cvt8(s[0], s[1]);
    }
    // B tile: 64x64 (weight rows) f32 -> f16
#pragma unroll
    for (int j = 0; j < 2; ++j) {
      const int flat = j * 2048 + tid * 8;
      const int r = flat >> 6, c = flat & 63;
      const float4* s = reinterpret_cast<const float4*>(Bw + (size_t)(nrow0 + r) * K + k0 + c);
      *reinterpret_cast<half8*>(&Bs[flat]) = cvt8(s[0], s[1]);
    }
    __syncthreads();
#pragma unroll
    for (int kk = 0; kk < 64; kk += 32) {
      half8 af[4], bf[2];
#pragma unroll
      for (int mi = 0; mi < 4; ++mi)
        af[mi] = *reinterpret_cast<const half8*>(
            &As[(wr * 64 + mi * 16 + (lane & 15)) * 64 + kk + 8 * (lane >> 4)]);
#pragma unroll
      for (int ni = 0; ni < 2; ++ni)
        bf[ni] = *reinterpret_cast<const half8*>(
            &Bs[(wc * 32 + ni * 16 + (lane & 15)) * 64 + kk + 8 * (lane >> 4)]);
#pragma unroll
      for (int mi = 0; mi < 4; ++mi) {
#pragma unroll
        for (int ni = 0; ni < 2; ++ni)
          acc[mi][ni] =
              __builtin_amdgcn_mfma_f32_16x16x32_f16(af[mi], bf[ni], acc[mi][ni], 0, 0, 0);
      }
    }
    __syncthreads();
  }

  // Epilogue: f32 acc -> f16 rbuf.  D layout: row = 4*(lane>>4)+e, col = lane&15.
#pragma unroll
  for (int mi = 0; mi < 4; ++mi) {
#pragma unroll
    for (int ni = 0; ni < 2; ++ni) {
#pragma unroll
      for (int e = 0; e < 4; ++e) {
        const int row = row0 + wr * 64 + mi * 16 + 4 * (lane >> 4) + e;
        const int col = colbase + wc * 32 + ni * 16 + (lane & 15);
        rbuf[(size_t)row * RB_LD + col] = (_Float16)acc[mi][ni][e];
      }
    }
  }
}

// ---------------- stage 2: pre = r @ [W2|U2]^T + fused epilogue -------------
// grid = 1024 blocks of 256 threads. Tile BM=128, BN=128, BK=64, K=512.
// k0<256 pulls from W2, k0>=256 from U2 (both [2048,256] f32 row-major).
__global__ __launch_bounds__(256)
void fgrnn_stage2(const _Float16* __restrict__ rbuf,
                  const float* __restrict__ W2, const float* __restrict__ U2,
                  const float* __restrict__ state,
                  const float* __restrict__ bg, const float* __restrict__ bu,
                  const float* __restrict__ zeta, const float* __restrict__ nu,
                  float* __restrict__ out) {
  const int bid = blockIdx.x;
  const int mtile = bid >> 4;  // 0..63
  const int ntile = bid & 15;  // 0..15
  const int row0 = mtile * 128;
  const int col0 = ntile * 128;

  __shared__ _Float16 As[128 * 64];
  __shared__ _Float16 Bs[128 * 64];

  const int tid = threadIdx.x;
  const int lane = tid & 63;
  const int w = tid >> 6;
  const int wr = w >> 1;
  const int wc = w & 1;

  f32x4 acc[4][4];
#pragma unroll
  for (int i = 0; i < 4; ++i) {
#pragma unroll
    for (int j = 0; j < 4; ++j) acc[i][j] = (f32x4){0.f, 0.f, 0.f, 0.f};
  }

  for (int k0 = 0; k0 < 512; k0 += 64) {
    // A tile: f16 copy from rbuf
#pragma unroll
    for (int j = 0; j < 4; ++j) {
      const int flat = j * 2048 + tid * 8;
      const int r = flat >> 6, c = flat & 63;
      *reinterpret_cast<uint4*>(&As[flat]) =
          *reinterpret_cast<const uint4*>(rbuf + (size_t)(row0 + r) * RB_LD + k0 + c);
    }
    // B tile: f32 -> f16 from W2 (k<256) or U2 (k>=256)
    const float* Bsrc = (k0 < 256) ? W2 : U2;
    const int kb = (k0 < 256) ? k0 : (k0 - 256);
#pragma unroll
    for (int j = 0; j < 4; ++j) {
      const int flat = j * 2048 + tid * 8;
      const int r = flat >> 6, c = flat & 63;
      const float4* s = reinterpret_cast<const float4*>(Bsrc + (size_t)(col0 + r) * RK + kb + c);
      *reinterpret_cast<half8*>(&Bs[flat]) = cvt8(s[0], s[1]);
    }
    __syncthreads();
#pragma unroll
    for (int kk = 0; kk < 64; kk += 32) {
      half8 af[4], bf[4];
#pragma unroll
      for (int mi = 0; mi < 4; ++mi)
        af[mi] = *reinterpret_cast<const half8*>(
            &As[(wr * 64 + mi * 16 + (lane & 15)) * 64 + kk + 8 * (lane >> 4)]);
#pragma unroll
      for (int ni = 0; ni < 4; ++ni)
        bf[ni] = *reinterpret_cast<const half8*>(
            &Bs[(wc * 64 + ni * 16 + (lane & 15)) * 64 + kk + 8 * (lane >> 4)]);
#pragma unroll
      for (int mi = 0; mi < 4; ++mi) {
#pragma unroll
        for (int ni = 0; ni < 4; ++ni)
          acc[mi][ni] =
              __builtin_amdgcn_mfma_f32_16x16x32_f16(af[mi], bf[ni], acc[mi][ni], 0, 0, 0);
      }
    }
    __syncthreads();
  }

  // Fused FastGRNN epilogue
  const float sz = 1.f / (1.f + expf(-zeta[0]));
  const float sn = 1.f / (1.f + expf(-nu[0]));
#pragma unroll
  for (int mi = 0; mi < 4; ++mi) {
#pragma unroll
    for (int ni = 0; ni < 4; ++ni) {
#pragma unroll
      for (int e = 0; e < 4; ++e) {
        const int row = row0 + wr * 64 + mi * 16 + 4 * (lane >> 4) + e;
        const int col = col0 + wc * 64 + ni * 16 + (lane & 15);
        const float pre = acc[mi][ni][e];
        const float zg = 1.f / (1.f + expf(-(pre + bg[col])));
        const float hc = tanhf(pre + bu[col]);
        const float sv = state[(size_t)row * DH + col];
        out[(size_t)row * DH + col] = zg * sv + (sz * (1.f - zg) + sn) * hc;
      }
    }
  }
}

extern "C" void kernel_launch(void* const* d_in, const int* in_sizes, int n_in,
                              void* d_out, int out_size, void* d_ws, size_t ws_size,
                              hipStream_t stream) {
  const float* input = (const float*)d_in[0];
  const float* state = (const float*)d_in[1];
  const float* W1 = (const float*)d_in[2];
  const float* W2 = (const float*)d_in[3];
  const float* U1 = (const float*)d_in[4];
  const float* U2 = (const float*)d_in[5];
  const float* bg = (const float*)d_in[6];
  const float* bu = (const float*)d_in[7];
  const float* zeta = (const float*)d_in[8];
  const float* nu = (const float*)d_in[9];
  float* out = (float*)d_out;
  _Float16* rbuf = (_Float16*)d_ws;  // 8192*512*2 = 8 MB

  fgrnn_stage1<<<512, 256, 0, stream>>>(input, state, W1, U1, rbuf);
  fgrnn_stage2<<<1024, 256, 0, stream>>>(rbuf, W2, U2, state, bg, bu, zeta, nu, out);
}

// Round 2
// 110.568 us; speedup vs baseline: 1.7204x; 1.7204x over previous
//
#include <hip/hip_runtime.h>
#include <hip/hip_fp16.h>
#include <cstdint>
#include <cstddef>

// FastGRNN cell, MI355X fp16-MFMA, v2.
// rbuf[8192][768] = [ x@W1^T (256) | h@U1[:, :1024]^T (256) | h@U1[:,1024:]^T (256) ]
// pre = rbuf @ [W2 | U2 | U2]^T   (K=768)
// out = sig(pre+bg)*h + (sig(zeta)*(1-sig(pre+bg)) + sig(nu)) * tanh(pre+bu)

typedef _Float16 half8 __attribute__((ext_vector_type(8)));
typedef float f32x4 __attribute__((ext_vector_type(4)));

#define DIN 1024
#define DH 2048
#define RK 256
#define RB_LD 768

__device__ __forceinline__ half8 cvt8(const float4 a, const float4 b) {
  half8 h;
  h[0] = (_Float16)a.x; h[1] = (_Float16)a.y; h[2] = (_Float16)a.z; h[3] = (_Float16)a.w;
  h[4] = (_Float16)b.x; h[5] = (_Float16)b.y; h[6] = (_Float16)b.z; h[7] = (_Float16)b.w;
  return h;
}

// ---------------- stage 1: low-rank projections, A read once ----------------
// 384 blocks x 512 threads. BM=64, BN=256, BK=64, 16 K-iters for every block.
// grp 0: x@W1^T (K 0..1023);  grp 1: h@U1^T K 0..1023;  grp 2: h@U1^T K 1024..2047.
// 8 waves in 2x4; each wave owns 32x64 (acc[2][4]).
__global__ __launch_bounds__(512)
void fgrnn_stage1(const float* __restrict__ x, const float* __restrict__ h,
                  const float* __restrict__ W1, const float* __restrict__ U1,
                  _Float16* __restrict__ rbuf) {
  const int bid = blockIdx.x;
  const int grp = bid >> 7;         // 0,1,2
  const int mtile = bid & 127;
  const float* A = grp ? h : x;
  const float* Bw = grp ? U1 : W1;
  const int KA = grp ? DH : DIN;    // row stride of both A and weights
  const int kbase = (grp == 2) ? 1024 : 0;
  const int colbase = grp << 8;
  const int row0 = mtile * 64;

  __shared__ _Float16 As[64 * 64];   // XOR-swizzled: elem c ^= (r&7)<<3
  __shared__ _Float16 Bs[256 * 64];

  const int tid = threadIdx.x;
  const int lane = tid & 63;
  const int w = tid >> 6;
  const int wr = w >> 2, wc = w & 3;

  f32x4 acc[2][4];
#pragma unroll
  for (int i = 0; i < 2; ++i)
#pragma unroll
    for (int j = 0; j < 4; ++j) acc[i][j] = (f32x4){0.f, 0.f, 0.f, 0.f};

  const int sr = tid >> 3;          // staging row (A: 0..63; B: +j*64)
  const int sc = (tid & 7) * 8;     // staging col (8 f32 per thread-chunk)

  float4 pa0, pa1, pb[8];

  auto LOADG = [&](int it) {
    const int k0 = kbase + it * 64;
    const float* sa = A + (size_t)(row0 + sr) * KA + k0 + sc;
    pa0 = *reinterpret_cast<const float4*>(sa);
    pa1 = *reinterpret_cast<const float4*>(sa + 4);
#pragma unroll
    for (int j = 0; j < 4; ++j) {
      const float* sb = Bw + (size_t)(j * 64 + sr) * KA + k0 + sc;
      pb[2 * j] = *reinterpret_cast<const float4*>(sb);
      pb[2 * j + 1] = *reinterpret_cast<const float4*>(sb + 4);
    }
  };
  auto STORE = [&]() {
    *reinterpret_cast<half8*>(&As[sr * 64 + (sc ^ ((sr & 7) << 3))]) = cvt8(pa0, pa1);
#pragma unroll
    for (int j = 0; j < 4; ++j) {
      const int r = j * 64 + sr;
      *reinterpret_cast<half8*>(&Bs[r * 64 + (sc ^ ((r & 7) << 3))]) =
          cvt8(pb[2 * j], pb[2 * j + 1]);
    }
  };

  LOADG(0);
  STORE();
  __syncthreads();

  for (int it = 0; it < 16; ++it) {
    const bool more = (it + 1 < 16);
    if (more) LOADG(it + 1);   // regs prefetch; latency hides under MFMA below
#pragma unroll
    for (int kk = 0; kk < 64; kk += 32) {
      half8 af[2], bf[4];
#pragma unroll
      for (int mi = 0; mi < 2; ++mi) {
        const int r = wr * 32 + mi * 16 + (lane & 15);
        af[mi] = *reinterpret_cast<const half8*>(
            &As[r * 64 + ((kk + 8 * (lane >> 4)) ^ ((r & 7) << 3))]);
      }
#pragma unroll
      for (int ni = 0; ni < 4; ++ni) {
        const int r = wc * 64 + ni * 16 + (lane & 15);
        bf[ni] = *reinterpret_cast<const half8*>(
            &Bs[r * 64 + ((kk + 8 * (lane >> 4)) ^ ((r & 7) << 3))]);
      }
#pragma unroll
      for (int mi = 0; mi < 2; ++mi)
#pragma unroll
        for (int ni = 0; ni < 4; ++ni)
          acc[mi][ni] =
              __builtin_amdgcn_mfma_f32_16x16x32_f16(af[mi], bf[ni], acc[mi][ni], 0, 0, 0);
    }
    if (more) {
      __syncthreads();
      STORE();
    }
    __syncthreads();
  }

  // D layout: row = 4*(lane>>4)+e, col = lane&15 (f16 family, verified R1)
#pragma unroll
  for (int mi = 0; mi < 2; ++mi)
#pragma unroll
    for (int ni = 0; ni < 4; ++ni)
#pragma unroll
      for (int e = 0; e < 4; ++e) {
        const int row = row0 + wr * 32 + mi * 16 + 4 * (lane >> 4) + e;
        const int col = colbase + wc * 64 + ni * 16 + (lane & 15);
        rbuf[(size_t)row * RB_LD + col] = (_Float16)acc[mi][ni][e];
      }
}

// ---------------- stage 2: pre = rbuf @ [W2|U2|U2]^T + fused epilogue ------
// 1024 blocks x 256 threads. BM=128, BN=128, BK=64, K=768 (12 iters).
__global__ __launch_bounds__(256)
void fgrnn_stage2(const _Float16* __restrict__ rbuf,
                  const float* __restrict__ W2, const float* __restrict__ U2,
                  const float* __restrict__ state,
                  const float* __restrict__ bg, const float* __restrict__ bu,
                  const float* __restrict__ zeta, const float* __restrict__ nu,
                  float* __restrict__ out) {
  const int bid = blockIdx.x;
  const int mtile = bid >> 4;  // 0..63
  const int ntile = bid & 15;  // 0..15
  const int row0 = mtile * 128;
  const int col0 = ntile * 128;

  __shared__ _Float16 As[128 * 64];
  __shared__ _Float16 Bs[128 * 64];

  const int tid = threadIdx.x;
  const int lane = tid & 63;
  const int w = tid >> 6;
  const int wr = w >> 1, wc = w & 1;

  f32x4 acc[4][4];
#pragma unroll
  for (int i = 0; i < 4; ++i)
#pragma unroll
    for (int j = 0; j < 4; ++j) acc[i][j] = (f32x4){0.f, 0.f, 0.f, 0.f};

  const int sr = tid >> 3;        // 0..31
  const int sc = (tid & 7) * 8;

  uint4 pa[4];
  float4 pb[8];

  auto LOADG = [&](int it) {
    const int k0 = it * 64;
    const int sel = k0 >> 8;                  // 0:W2  1:U2(lo)  2:U2(hi)
    const float* Bsrc = sel ? U2 : W2;
    const int kb = k0 - (sel << 8);
#pragma unroll
    for (int j = 0; j < 4; ++j) {
      const int r = j * 32 + sr;
      pa[j] = *reinterpret_cast<const uint4*>(rbuf + (size_t)(row0 + r) * RB_LD + k0 + sc);
      const float* sb = Bsrc + (size_t)(col0 + r) * RK + kb + sc;
      pb[2 * j] = *reinterpret_cast<const float4*>(sb);
      pb[2 * j + 1] = *reinterpret_cast<const float4*>(sb + 4);
    }
  };
  auto STORE = [&]() {
#pragma unroll
    for (int j = 0; j < 4; ++j) {
      const int r = j * 32 + sr;
      const int off = r * 64 + (sc ^ ((r & 7) << 3));
      *reinterpret_cast<half8*>(&As[off]) = *reinterpret_cast<half8*>(&pa[j]);
      *reinterpret_cast<half8*>(&Bs[off]) = cvt8(pb[2 * j], pb[2 * j + 1]);
    }
  };

  LOADG(0);
  STORE();
  __syncthreads();

  for (int it = 0; it < 12; ++it) {
    const bool more = (it + 1 < 12);
    if (more) LOADG(it + 1);
#pragma unroll
    for (int kk = 0; kk < 64; kk += 32) {
      half8 af[4], bf[4];
#pragma unroll
      for (int mi = 0; mi < 4; ++mi) {
        const int r = wr * 64 + mi * 16 + (lane & 15);
        af[mi] = *reinterpret_cast<const half8*>(
            &As[r * 64 + ((kk + 8 * (lane >> 4)) ^ ((r & 7) << 3))]);
      }
#pragma unroll
      for (int ni = 0; ni < 4; ++ni) {
        const int r = wc * 64 + ni * 16 + (lane & 15);
        bf[ni] = *reinterpret_cast<const half8*>(
            &Bs[r * 64 + ((kk + 8 * (lane >> 4)) ^ ((r & 7) << 3))]);
      }
#pragma unroll
      for (int mi = 0; mi < 4; ++mi)
#pragma unroll
        for (int ni = 0; ni < 4; ++ni)
          acc[mi][ni] =
              __builtin_amdgcn_mfma_f32_16x16x32_f16(af[mi], bf[ni], acc[mi][ni], 0, 0, 0);
    }
    if (more) {
      __syncthreads();
      STORE();
    }
    __syncthreads();
  }

  // Fused FastGRNN epilogue
  const float sz = 1.f / (1.f + __expf(-zeta[0]));
  const float sn = 1.f / (1.f + __expf(-nu[0]));
#pragma unroll
  for (int mi = 0; mi < 4; ++mi)
#pragma unroll
    for (int ni = 0; ni < 4; ++ni) {
      const int col = col0 + wc * 64 + ni * 16 + (lane & 15);
      const float bgc = bg[col];
      const float buc = bu[col];
#pragma unroll
      for (int e = 0; e < 4; ++e) {
        const int row = row0 + wr * 64 + mi * 16 + 4 * (lane >> 4) + e;
        const float pre = acc[mi][ni][e];
        const float zg = 1.f / (1.f + __expf(-(pre + bgc)));
        // tanh(p) = 1 - 2/(exp(2p)+1)
        const float hc = 1.f - 2.f / (1.f + __expf(2.f * (pre + buc)));
        const float sv = state[(size_t)row * DH + col];
        out[(size_t)row * DH + col] = zg * sv + (sz * (1.f - zg) + sn) * hc;
      }
    }
}

extern "C" void kernel_launch(void* const* d_in, const int* in_sizes, int n_in,
                              void* d_out, int out_size, void* d_ws, size_t ws_size,
                              hipStream_t stream) {
  const float* input = (const float*)d_in[0];
  const float* state = (const float*)d_in[1];
  const float* W1 = (const float*)d_in[2];
  const float* W2 = (const float*)d_in[3];
  const float* U1 = (const float*)d_in[4];
  const float* U2 = (const float*)d_in[5];
  const float* bg = (const float*)d_in[6];
  const float* bu = (const float*)d_in[7];
  const float* zeta = (const float*)d_in[8];
  const float* nu = (const float*)d_in[9];
  float* out = (float*)d_out;
  _Float16* rbuf = (_Float16*)d_ws;  // 8192*768*2 = 12.6 MB

  fgrnn_stage1<<<384, 512, 0, stream>>>(input, state, W1, U1, rbuf);
  fgrnn_stage2<<<1024, 256, 0, stream>>>(rbuf, W2, U2, state, bg, bu, zeta, nu, out);
}

// Round 3
// 77.867 us; speedup vs baseline: 2.4429x; 1.4200x over previous
//
#include <hip/hip_runtime.h>
#include <hip/hip_fp16.h>
#include <cstdint>
#include <cstddef>

// FastGRNN cell, MI355X fp16-MFMA, v3.
// prep:   W1,U1,W2,U2 (f32) -> wb (f16) in d_ws
// stage1: rbuf[8192][768] = [ x@W1^T | h@U1[:,:1024]^T | h@U1[:,1024:]^T ]  (f16)
// stage2: pre = [wx | uh0+uh1] @ [W2|U2]^T  (K=512), fused sigmoid/tanh epilogue.

typedef _Float16 half8 __attribute__((ext_vector_type(8)));
typedef float f32x4 __attribute__((ext_vector_type(4)));

#define DIN 1024
#define DH 2048
#define RK 256
#define RB_LD 768
// wb half-offsets
#define OFF_W1H 0
#define OFF_U1H 262144
#define OFF_W2H 786432
#define OFF_U2H 1310720

__device__ __forceinline__ half8 cvt8(const float4 a, const float4 b) {
  half8 h;
  h[0] = (_Float16)a.x; h[1] = (_Float16)a.y; h[2] = (_Float16)a.z; h[3] = (_Float16)a.w;
  h[4] = (_Float16)b.x; h[5] = (_Float16)b.y; h[6] = (_Float16)b.z; h[7] = (_Float16)b.w;
  return h;
}

// ---------------- prep: weights f32 -> f16, one pass ------------------------
// quads: W1 65536 | U1 131072 | W2 131072 | U2 131072  (total 458752)
__global__ __launch_bounds__(256)
void fgrnn_prep(const float* __restrict__ W1, const float* __restrict__ U1,
                const float* __restrict__ W2, const float* __restrict__ U2,
                _Float16* __restrict__ wb) {
  const int q = blockIdx.x * 256 + threadIdx.x;
  const float* src;
  int rel;
  if (q < 65536) { src = W1; rel = q; }
  else if (q < 196608) { src = U1; rel = q - 65536; }
  else if (q < 327680) { src = W2; rel = q - 196608; }
  else { src = U2; rel = q - 327680; }
  const float4 v = reinterpret_cast<const float4*>(src)[rel];
  union { _Float16 h[4]; uint2 u; } cv;
  cv.h[0] = (_Float16)v.x; cv.h[1] = (_Float16)v.y;
  cv.h[2] = (_Float16)v.z; cv.h[3] = (_Float16)v.w;
  reinterpret_cast<uint2*>(wb)[q] = cv.u;
}

// ---------------- stage 1: low-rank projections, A read once ----------------
// 384 blocks x 512 threads. BM=64, BN=256, BK=64, 16 K-iters every block.
// grp 0: x@W1^T (K 0..1023); grp 1: h@U1^T K 0..1023; grp 2: h@U1^T K 1024..2047.
__global__ __launch_bounds__(512)
void fgrnn_stage1(const float* __restrict__ x, const float* __restrict__ h,
                  const _Float16* __restrict__ wb, _Float16* __restrict__ rbuf) {
  const int bid = blockIdx.x;
  const int grp = bid >> 7;         // 0,1,2
  const int mtile = bid & 127;
  const float* A = grp ? h : x;
  const _Float16* Bw = grp ? (wb + OFF_U1H) : (wb + OFF_W1H);
  const int KA = grp ? DH : DIN;
  const int kbase = (grp == 2) ? 1024 : 0;
  const int colbase = grp << 8;
  const int row0 = mtile * 64;

  __shared__ _Float16 As[64 * 64];   // swizzle: c ^= (r&7)<<3
  __shared__ _Float16 Bs[256 * 64];

  const int tid = threadIdx.x;
  const int lane = tid & 63;
  const int w = tid >> 6;
  const int wr = w >> 2, wc = w & 3;

  f32x4 acc[2][4];
#pragma unroll
  for (int i = 0; i < 2; ++i)
#pragma unroll
    for (int j = 0; j < 4; ++j) acc[i][j] = (f32x4){0.f, 0.f, 0.f, 0.f};

  const int sr = tid >> 3;          // 0..63
  const int sc = (tid & 7) * 8;

  float4 pa0, pa1;
  half8 pb[4];

  auto LOADG = [&](int it) {
    const int k0 = kbase + it * 64;
    const float* sa = A + (size_t)(row0 + sr) * KA + k0 + sc;
    pa0 = *reinterpret_cast<const float4*>(sa);
    pa1 = *reinterpret_cast<const float4*>(sa + 4);
#pragma unroll
    for (int j = 0; j < 4; ++j)
      pb[j] = *reinterpret_cast<const half8*>(Bw + (size_t)(j * 64 + sr) * KA + k0 + sc);
  };
  auto STORE = [&]() {
    *reinterpret_cast<half8*>(&As[sr * 64 + (sc ^ ((sr & 7) << 3))]) = cvt8(pa0, pa1);
#pragma unroll
    for (int j = 0; j < 4; ++j) {
      const int r = j * 64 + sr;
      *reinterpret_cast<half8*>(&Bs[r * 64 + (sc ^ ((r & 7) << 3))]) = pb[j];
    }
  };

  LOADG(0);
  STORE();
  __syncthreads();

  for (int it = 0; it < 16; ++it) {
    const bool more = (it + 1 < 16);
    if (more) LOADG(it + 1);
#pragma unroll
    for (int kk = 0; kk < 64; kk += 32) {
      half8 af[2], bf[4];
#pragma unroll
      for (int mi = 0; mi < 2; ++mi) {
        const int r = wr * 32 + mi * 16 + (lane & 15);
        af[mi] = *reinterpret_cast<const half8*>(
            &As[r * 64 + ((kk + 8 * (lane >> 4)) ^ ((r & 7) << 3))]);
      }
#pragma unroll
      for (int ni = 0; ni < 4; ++ni) {
        const int r = wc * 64 + ni * 16 + (lane & 15);
        bf[ni] = *reinterpret_cast<const half8*>(
            &Bs[r * 64 + ((kk + 8 * (lane >> 4)) ^ ((r & 7) << 3))]);
      }
#pragma unroll
      for (int mi = 0; mi < 2; ++mi)
#pragma unroll
        for (int ni = 0; ni < 4; ++ni)
          acc[mi][ni] =
              __builtin_amdgcn_mfma_f32_16x16x32_f16(af[mi], bf[ni], acc[mi][ni], 0, 0, 0);
    }
    if (more) {
      __syncthreads();
      STORE();
    }
    __syncthreads();
  }

#pragma unroll
  for (int mi = 0; mi < 2; ++mi)
#pragma unroll
    for (int ni = 0; ni < 4; ++ni)
#pragma unroll
      for (int e = 0; e < 4; ++e) {
        const int row = row0 + wr * 32 + mi * 16 + 4 * (lane >> 4) + e;
        const int col = colbase + wc * 64 + ni * 16 + (lane & 15);
        rbuf[(size_t)row * RB_LD + col] = (_Float16)acc[mi][ni][e];
      }
}

// ---------------- stage 2: pre = [wx|uh0+uh1] @ [W2|U2]^T, K=512 ------------
// 2048 blocks x 256 threads. BM=64, BN=128, BK=64, 8 K-iters.
// 4 waves 2x2; wave tile 32x64 (acc[2][4]).
__global__ __launch_bounds__(256)
void fgrnn_stage2(const _Float16* __restrict__ rbuf, const _Float16* __restrict__ wb,
                  const float* __restrict__ state,
                  const float* __restrict__ bg, const float* __restrict__ bu,
                  const float* __restrict__ zeta, const float* __restrict__ nu,
                  float* __restrict__ out) {
  const int bid = blockIdx.x;
  const int mtile = bid >> 4;   // 0..127
  const int ntile = bid & 15;   // 0..15
  const int row0 = mtile * 64;
  const int col0 = ntile * 128;
  const _Float16* W2h = wb + OFF_W2H;
  const _Float16* U2h = wb + OFF_U2H;

  __shared__ _Float16 As[64 * 64];
  __shared__ _Float16 Bs[128 * 64];

  const int tid = threadIdx.x;
  const int lane = tid & 63;
  const int w = tid >> 6;
  const int wr = w >> 1, wc = w & 1;

  f32x4 acc[2][4];
#pragma unroll
  for (int i = 0; i < 2; ++i)
#pragma unroll
    for (int j = 0; j < 4; ++j) acc[i][j] = (f32x4){0.f, 0.f, 0.f, 0.f};

  const int sr = tid >> 3;      // 0..31
  const int sc = (tid & 7) * 8;

  half8 pa[2], pa2[2], pb[4];

  auto LOADG = [&](int it) {
    const int k0 = it * 64;
#pragma unroll
    for (int j = 0; j < 2; ++j) {
      const _Float16* p = rbuf + (size_t)(row0 + j * 32 + sr) * RB_LD + k0 + sc;
      pa[j] = *reinterpret_cast<const half8*>(p);
      if (k0 >= 256) pa2[j] = *reinterpret_cast<const half8*>(p + 256);
    }
    const _Float16* Bh = (k0 < 256) ? W2h : U2h;
    const int kb = k0 & 255;
#pragma unroll
    for (int j = 0; j < 4; ++j)
      pb[j] = *reinterpret_cast<const half8*>(Bh + (size_t)(col0 + j * 32 + sr) * RK + kb + sc);
  };
  auto STORE = [&](int it) {
    const int k0 = it * 64;
#pragma unroll
    for (int j = 0; j < 2; ++j) {
      const int r = j * 32 + sr;
      half8 v = pa[j];
      if (k0 >= 256) v = v + pa2[j];   // uh = uh0 + uh1 (v_pk_add_f16)
      *reinterpret_cast<half8*>(&As[r * 64 + (sc ^ ((r & 7) << 3))]) = v;
    }
#pragma unroll
    for (int j = 0; j < 4; ++j) {
      const int r = j * 32 + sr;
      *reinterpret_cast<half8*>(&Bs[r * 64 + (sc ^ ((r & 7) << 3))]) = pb[j];
    }
  };

  LOADG(0);
  STORE(0);
  __syncthreads();

  for (int it = 0; it < 8; ++it) {
    const bool more = (it + 1 < 8);
    if (more) LOADG(it + 1);
#pragma unroll
    for (int kk = 0; kk < 64; kk += 32) {
      half8 af[2], bf[4];
#pragma unroll
      for (int mi = 0; mi < 2; ++mi) {
        const int r = wr * 32 + mi * 16 + (lane & 15);
        af[mi] = *reinterpret_cast<const half8*>(
            &As[r * 64 + ((kk + 8 * (lane >> 4)) ^ ((r & 7) << 3))]);
      }
#pragma unroll
      for (int ni = 0; ni < 4; ++ni) {
        const int r = wc * 64 + ni * 16 + (lane & 15);
        bf[ni] = *reinterpret_cast<const half8*>(
            &Bs[r * 64 + ((kk + 8 * (lane >> 4)) ^ ((r & 7) << 3))]);
      }
#pragma unroll
      for (int mi = 0; mi < 2; ++mi)
#pragma unroll
        for (int ni = 0; ni < 4; ++ni)
          acc[mi][ni] =
              __builtin_amdgcn_mfma_f32_16x16x32_f16(af[mi], bf[ni], acc[mi][ni], 0, 0, 0);
    }
    if (more) {
      __syncthreads();
      STORE(it + 1);
    }
    __syncthreads();
  }

  // Fused epilogue: fast exp2/rcp (1-instr transcendentals; asymptotes correct)
  const float LOG2E = 1.44269504f;
  const float sz = __builtin_amdgcn_rcpf(1.f + __builtin_amdgcn_exp2f(-zeta[0] * LOG2E));
  const float sn = __builtin_amdgcn_rcpf(1.f + __builtin_amdgcn_exp2f(-nu[0] * LOG2E));
#pragma unroll
  for (int mi = 0; mi < 2; ++mi)
#pragma unroll
    for (int ni = 0; ni < 4; ++ni) {
      const int col = col0 + wc * 64 + ni * 16 + (lane & 15);
      const float bgc = bg[col];
      const float buc = bu[col];
#pragma unroll
      for (int e = 0; e < 4; ++e) {
        const int row = row0 + wr * 32 + mi * 16 + 4 * (lane >> 4) + e;
        const float pre = acc[mi][ni][e];
        const float zg =
            __builtin_amdgcn_rcpf(1.f + __builtin_amdgcn_exp2f(-(pre + bgc) * LOG2E));
        const float hc =
            1.f - 2.f * __builtin_amdgcn_rcpf(
                            1.f + __builtin_amdgcn_exp2f((pre + buc) * (2.f * LOG2E)));
        const float sv = state[(size_t)row * DH + col];
        out[(size_t)row * DH + col] = zg * sv + (sz * (1.f - zg) + sn) * hc;
      }
    }
}

extern "C" void kernel_launch(void* const* d_in, const int* in_sizes, int n_in,
                              void* d_out, int out_size, void* d_ws, size_t ws_size,
                              hipStream_t stream) {
  const float* input = (const float*)d_in[0];
  const float* state = (const float*)d_in[1];
  const float* W1 = (const float*)d_in[2];
  const float* W2 = (const float*)d_in[3];
  const float* U1 = (const float*)d_in[4];
  const float* U2 = (const float*)d_in[5];
  const float* bg = (const float*)d_in[6];
  const float* bu = (const float*)d_in[7];
  const float* zeta = (const float*)d_in[8];
  const float* nu = (const float*)d_in[9];
  float* out = (float*)d_out;
  _Float16* rbuf = (_Float16*)d_ws;                    // 8192*768*2 = 12.6 MB
  _Float16* wb = (_Float16*)d_ws + (size_t)8192 * 768; // +3.67 MB weights f16

  fgrnn_prep<<<1792, 256, 0, stream>>>(W1, U1, W2, U2, wb);
  fgrnn_stage1<<<384, 512, 0, stream>>>(input, state, wb, rbuf);
  fgrnn_stage2<<<2048, 256, 0, stream>>>(rbuf, wb, state, bg, bu, zeta, nu, out);
}